// Round 11
// baseline (827.208 us; speedup 1.0000x reference)
//
#include <hip/hip_runtime.h>
#include <hip/hip_bf16.h>

#define T_DIM 512
#define B_DIM 16
#define D_DIM 1024
#define N_DIM 512

// c-fold: store S' = C*S so the exp2 argument is a single fma.
// C = 2*log2(e); tanh via exp2: tanh(x) = 1 - 2/(exp2(C*x)+1)
#define C_FOLD  2.885390082f
#define INV_C   0.3465735903f

typedef short s16x8 __attribute__((ext_vector_type(8)));
typedef float f32x4 __attribute__((ext_vector_type(4)));
typedef float f32x2 __attribute__((ext_vector_type(2)));

__device__ __forceinline__ unsigned short f2bf(float f) {
    unsigned u = __float_as_uint(f);
    unsigned r = (u + 0x7fffu + ((u >> 16) & 1u)) >> 16;
    return (unsigned short)r;
}

// sum over the 32 lanes of this half-wave, result broadcast to all 32.
// (R3/R6/R10-proven: 4 DPP adds + 1 ds_swizzle xor16. No barrier needed.)
__device__ __forceinline__ float half32_sum(float x) {
    x += __int_as_float(__builtin_amdgcn_update_dpp(0, __float_as_int(x), 0xB1,  0xf, 0xf, true)); // quad_perm[1,0,3,2]
    x += __int_as_float(__builtin_amdgcn_update_dpp(0, __float_as_int(x), 0x4E,  0xf, 0xf, true)); // quad_perm[2,3,0,1]
    x += __int_as_float(__builtin_amdgcn_update_dpp(0, __float_as_int(x), 0x124, 0xf, 0xf, true)); // row_ror:4
    x += __int_as_float(__builtin_amdgcn_update_dpp(0, __float_as_int(x), 0x128, 0xf, 0xf, true)); // row_ror:8
    x += __int_as_float(__builtin_amdgcn_ds_swizzle(__float_as_int(x), 0x401F));                   // xor 16
    return x;
}

// pairwise tanh' on an f32x2 (S' domain): one rcp for two elements.
// (R10-proven.) Overflow of the product only matters when the partner term
// is >=2^38, where tanh==1 to 1e-11 anyway.
__device__ __forceinline__ f32x2 tanh2p(f32x2 arg, f32x2 Cv, f32x2 M2Cv) {
    float e0 = __builtin_amdgcn_exp2f(arg.x) + 1.0f;
    float e1 = __builtin_amdgcn_exp2f(arg.y) + 1.0f;
    float r  = __builtin_amdgcn_rcpf(e0 * e1);
    f32x2 w; w.x = e1 * r; w.y = e0 * r;
    return Cv + w * M2Cv;
}

// ---------------- projection GEMM: C[m,n] = sum_d x[m,d] * W[n,d] ----------
// v output pre-scaled by C_FOLD (scan works in S' = C*S domain).
__global__ __launch_bounds__(256) void proj_gemm(
    const float* __restrict__ x,
    const float* __restrict__ Wk,
    const float* __restrict__ Wv,
    const float* __restrict__ Wq,
    float* __restrict__ kbuf, float* __restrict__ vbuf, float* __restrict__ qbuf)
{
    const float* W = (blockIdx.z == 0) ? Wk : (blockIdx.z == 1) ? Wv : Wq;
    float* out = (blockIdx.z == 0) ? kbuf : (blockIdx.z == 1) ? vbuf : qbuf;
    const float oscale = (blockIdx.z == 1) ? C_FOLD : 1.0f;

    __shared__ __align__(16) unsigned short As[64 * 40];
    __shared__ __align__(16) unsigned short Bs[64 * 40];

    const int tid  = threadIdx.x;
    const int m0   = blockIdx.x * 64;
    const int n0   = blockIdx.y * 64;
    const int wave = tid >> 6;
    const int lane = tid & 63;
    const int l15  = lane & 15;
    const int quad = lane >> 4;

    const int srow = tid >> 2;
    const int scol = (tid & 3) * 8;

    f32x4 acc[4];
#pragma unroll
    for (int i = 0; i < 4; ++i) acc[i] = (f32x4)0.0f;

    for (int k0 = 0; k0 < D_DIM; k0 += 32) {
        __syncthreads();
        {
            const float* srcA = &x[(size_t)(m0 + srow) * D_DIM + k0 + scol];
            float4 a0 = *(const float4*)srcA;
            float4 a1 = *(const float4*)(srcA + 4);
            uint4 pa;
            pa.x = (unsigned)f2bf(a0.x) | ((unsigned)f2bf(a0.y) << 16);
            pa.y = (unsigned)f2bf(a0.z) | ((unsigned)f2bf(a0.w) << 16);
            pa.z = (unsigned)f2bf(a1.x) | ((unsigned)f2bf(a1.y) << 16);
            pa.w = (unsigned)f2bf(a1.z) | ((unsigned)f2bf(a1.w) << 16);
            *(uint4*)&As[srow * 40 + scol] = pa;

            const float* srcB = &W[(size_t)(n0 + srow) * D_DIM + k0 + scol];
            float4 b0 = *(const float4*)srcB;
            float4 b1 = *(const float4*)(srcB + 4);
            uint4 pb;
            pb.x = (unsigned)f2bf(b0.x) | ((unsigned)f2bf(b0.y) << 16);
            pb.y = (unsigned)f2bf(b0.z) | ((unsigned)f2bf(b0.w) << 16);
            pb.z = (unsigned)f2bf(b1.x) | ((unsigned)f2bf(b1.y) << 16);
            pb.w = (unsigned)f2bf(b1.z) | ((unsigned)f2bf(b1.w) << 16);
            *(uint4*)&Bs[srow * 40 + scol] = pb;
        }
        __syncthreads();
        s16x8 af = *(const s16x8*)&As[(wave * 16 + l15) * 40 + quad * 8];
#pragma unroll
        for (int nt = 0; nt < 4; ++nt) {
            s16x8 bf = *(const s16x8*)&Bs[(nt * 16 + l15) * 40 + quad * 8];
            acc[nt] = __builtin_amdgcn_mfma_f32_16x16x32_bf16(af, bf, acc[nt], 0, 0, 0);
        }
    }
#pragma unroll
    for (int nt = 0; nt < 4; ++nt) {
#pragma unroll
        for (int rg = 0; rg < 4; ++rg) {
            int row = m0 + wave * 16 + quad * 4 + rg;
            int col = n0 + nt * 16 + l15;
            out[(size_t)row * N_DIM + col] = acc[nt][rg] * oscale;
        }
    }
}

// ---------------- k row-normalization (in place) ---------------------------
__global__ __launch_bounds__(256) void knorm(float* __restrict__ kbuf)
{
    const int wave = threadIdx.x >> 6;
    const int lane = threadIdx.x & 63;
    const int row  = blockIdx.x * 4 + wave;
    float* p = &kbuf[(size_t)row * N_DIM + lane * 8];
    float4 a = *(const float4*)p;
    float4 b = *(const float4*)(p + 4);
    float s = a.x*a.x + a.y*a.y + a.z*a.z + a.w*a.w
            + b.x*b.x + b.y*b.y + b.z*b.z + b.w*b.w;
#pragma unroll
    for (int m = 1; m < 64; m <<= 1) s += __shfl_xor(s, m, 64);
    float inv = 1.0f / (sqrtf(s) + 1e-6f);
    a.x *= inv; a.y *= inv; a.z *= inv; a.w *= inv;
    b.x *= inv; b.y *= inv; b.z *= inv; b.w *= inv;
    *(float4*)p = a;
    *(float4*)(p + 4) = b;
}

// ---------------- sequential scan (barrier-free) ---------------------------
// grid(32, 16), block 256 = 4 waves. R6/R10 tile: lane (wv, h, tj) owns rows
// {4wv+2h, +1} x cols [16tj..16tj+15] of S' (= C*S). NO LDS, NO barriers:
// k/q/v read straight from global (coalesced b128, L1/L2-resident) with
// register double-buffered prefetch (ping-pong sets, manual 2x unroll), so
// the per-step vmcnt(0)+barrier drain of the staged version disappears and
// waves self-schedule. Reductions stay intra-wave (DPP + ds_swizzle).
__global__ __launch_bounds__(256) void scan_kernel(
    const float* __restrict__ kbuf, const float* __restrict__ vbuf,
    const float* __restrict__ qbuf, float* __restrict__ out)
{
    const int tid  = threadIdx.x;
    const int lane = tid & 63;
    const int wv   = tid >> 6;
    const int h    = lane >> 5;
    const int tj   = lane & 31;
    const int b    = blockIdx.y;
    const int i0   = blockIdx.x * 16;
    const int r0   = 4 * wv + 2 * h;   // local rows r0, r0+1

    const size_t BSTR = (size_t)B_DIM * N_DIM;   // per-step stride
    const float* kbase = kbuf + (size_t)b * N_DIM + 16 * tj;
    const float* qbase = qbuf + (size_t)b * N_DIM + 16 * tj;
    const float* vbase = vbuf + (size_t)b * N_DIM + i0 + r0;

    f32x2 SA[8], SB[8];
#pragma unroll
    for (int u = 0; u < 8; ++u) { SA[u] = (f32x2)0.0f; SB[u] = (f32x2)0.0f; }

    const f32x2 Cv   = {C_FOLD, C_FOLD};
    const f32x2 M2Cv = {-2.0f * C_FOLD, -2.0f * C_FOLD};

    f32x4 kA[4], qA[4], kB[4], qB[4];
    float2 vA, vB;

    // load t=0 into set A
#pragma unroll
    for (int u = 0; u < 4; ++u) {
        kA[u] = *(const f32x4*)(kbase + 4 * u);
        qA[u] = *(const f32x4*)(qbase + 4 * u);
    }
    vA = *(const float2*)vbase;

    // one scan step: prefetch t+1 into (KN,QN,VN), compute with (KC,QC,VC)
#define SCAN_STEP(T_IDX, KC, QC, VC, KN, QN, VN)                              \
    {                                                                         \
        const int tn = ((T_IDX) + 1 < T_DIM) ? (T_IDX) + 1 : (T_DIM - 1);     \
        const float* kpn = kbase + (size_t)tn * BSTR;                         \
        const float* qpn = qbase + (size_t)tn * BSTR;                         \
        _Pragma("unroll")                                                     \
        for (int u = 0; u < 4; ++u) {                                         \
            KN[u] = *(const f32x4*)(kpn + 4 * u);                             \
            QN[u] = *(const f32x4*)(qpn + 4 * u);                             \
        }                                                                     \
        VN = *(const float2*)(vbase + (size_t)tn * BSTR);                     \
                                                                              \
        f32x2 k2[8], q2[8];                                                   \
        _Pragma("unroll")                                                     \
        for (int u = 0; u < 4; ++u) {                                         \
            k2[2*u] = KC[u].xy; k2[2*u+1] = KC[u].zw;                         \
            q2[2*u] = QC[u].xy; q2[2*u+1] = QC[u].zw;                         \
        }                                                                     \
        /* racc' = sum_j S'_ij k_j */                                         \
        f32x2 pa0 = (f32x2)0.0f, pb0 = (f32x2)0.0f;                           \
        f32x2 pa1 = (f32x2)0.0f, pb1 = (f32x2)0.0f;                           \
        _Pragma("unroll")                                                     \
        for (int u = 0; u < 8; u += 2) {                                      \
            pa0 += SA[u] * k2[u];  pb0 += SA[u + 1] * k2[u + 1];              \
            pa1 += SB[u] * k2[u];  pb1 += SB[u + 1] * k2[u + 1];              \
        }                                                                     \
        const float racc0 = half32_sum(pa0.x + pa0.y + pb0.x + pb0.y);        \
        const float racc1 = half32_sum(pa1.x + pa1.y + pb1.x + pb1.y);        \
        const float dp0 = VC.x - racc0;   /* v pre-scaled by C */             \
        const float dp1 = VC.y - racc1;                                       \
        const f32x2 d0 = {dp0, dp0}, d1 = {dp1, dp1};                         \
        f32x2 sa0 = (f32x2)0.0f, sb0 = (f32x2)0.0f;                           \
        f32x2 sa1 = (f32x2)0.0f, sb1 = (f32x2)0.0f;                           \
        _Pragma("unroll")                                                     \
        for (int u = 0; u < 8; u += 2) {                                      \
            f32x2 nA0 = tanh2p(SA[u]     + d0 * k2[u],     Cv, M2Cv);         \
            f32x2 nB0 = tanh2p(SB[u]     + d1 * k2[u],     Cv, M2Cv);         \
            f32x2 nA1 = tanh2p(SA[u + 1] + d0 * k2[u + 1], Cv, M2Cv);         \
            f32x2 nB1 = tanh2p(SB[u + 1] + d1 * k2[u + 1], Cv, M2Cv);         \
            SA[u] = nA0; SB[u] = nB0; SA[u + 1] = nA1; SB[u + 1] = nB1;       \
            sa0 += nA0 * q2[u];     sa1 += nB0 * q2[u];                       \
            sb0 += nA1 * q2[u + 1]; sb1 += nB1 * q2[u + 1];                   \
        }                                                                     \
        const float sq0 = half32_sum(sa0.x + sa0.y + sb0.x + sb0.y);          \
        const float sq1 = half32_sum(sa1.x + sa1.y + sb1.x + sb1.y);          \
        if (tj == 0) {                                                        \
            const size_t ofs = (size_t)(T_IDX) * BSTR + (size_t)b * N_DIM;    \
            float s0 = sq0 * INV_C, s1 = sq1 * INV_C;                         \
            float g0 = __builtin_amdgcn_rcpf(                                 \
                1.0f + __builtin_amdgcn_exp2f(-s0 * 1.44269504f));            \
            float g1 = __builtin_amdgcn_rcpf(                                 \
                1.0f + __builtin_amdgcn_exp2f(-s1 * 1.44269504f));            \
            out[ofs + i0 + r0]     = s0 * s0 * g0;                            \
            out[ofs + i0 + r0 + 1] = s1 * s1 * g1;                            \
        }                                                                     \
    }

    for (int t = 0; t < T_DIM; t += 2) {
        SCAN_STEP(t,     kA, qA, vA, kB, qB, vB)
        SCAN_STEP(t + 1, kB, qB, vB, kA, qA, vA)
    }
#undef SCAN_STEP

    // S_final (true scale) -> d_out[T*B*N + ((b*N + i)*N + col)]
    const size_t base = (size_t)T_DIM * B_DIM * N_DIM;
    const size_t so0 = base + ((size_t)b * N_DIM + i0 + r0) * N_DIM + 16 * tj;
    const size_t so1 = so0 + N_DIM;
#pragma unroll
    for (int u = 0; u < 4; ++u) {
        float4 w0, w1;
        w0.x = SA[2*u].x   * INV_C; w0.y = SA[2*u].y   * INV_C;
        w0.z = SA[2*u+1].x * INV_C; w0.w = SA[2*u+1].y * INV_C;
        w1.x = SB[2*u].x   * INV_C; w1.y = SB[2*u].y   * INV_C;
        w1.z = SB[2*u+1].x * INV_C; w1.w = SB[2*u+1].y * INV_C;
        *(float4*)&out[so0 + 4 * u] = w0;
        *(float4*)&out[so1 + 4 * u] = w1;
    }
}

extern "C" void kernel_launch(void* const* d_in, const int* in_sizes, int n_in,
                              void* d_out, int out_size, void* d_ws, size_t ws_size,
                              hipStream_t stream) {
    const float* x  = (const float*)d_in[0];
    const float* Wk = (const float*)d_in[1];
    const float* Wv = (const float*)d_in[2];
    const float* Wq = (const float*)d_in[3];
    float* outp = (float*)d_out;

    const size_t MN = (size_t)T_DIM * B_DIM * N_DIM;
    float* kbuf = (float*)d_ws;
    float* vbuf = kbuf + MN;
    float* qbuf = vbuf + MN;

    proj_gemm<<<dim3(128, 8, 3), 256, 0, stream>>>(x, Wk, Wv, Wq, kbuf, vbuf, qbuf);
    knorm<<<2048, 256, 0, stream>>>(kbuf);
    scan_kernel<<<dim3(32, 16), 256, 0, stream>>>(kbuf, vbuf, qbuf, outp);
}